// Round 1
// baseline (87.869 us; speedup 1.0000x reference)
//
#include <hip/hip_runtime.h>

#define B   128
#define NE  14951
#define NR  1345
#define D   200
#define NL  116
#define D2  100
#define ET  8

// workspace float offsets
#define OFF_W   0        // [50][128][4]  = 25600 floats  (w[b][d], d-major chunks of 4)
#define OFF_A   25600    // [29][128][4]  = 14848 floats  (nh[b][l] - c[l])
#define OFF_WNF 40448    // [29][128][4]  = 14848 floats  (nf_weights[r_idx[b]][l])
#define OFF_NQ  55296    // [116]                        (-log2(e)/var[l])

__global__ __launch_bounds__(128) void prep_kernel(
    const int* __restrict__ e1_idx, const int* __restrict__ r_idx,
    const float* __restrict__ E, const float* __restrict__ R,
    const float* __restrict__ nf, const float* __restrict__ lit,
    const float* __restrict__ c, const float* __restrict__ var,
    float* __restrict__ ws)
{
    const int b = blockIdx.x;
    const int t = threadIdx.x;
    const int e1 = e1_idx[b];
    const int r  = r_idx[b];

    if (t < D2) {
        float e1r = E[e1 * D + t],      e1i = E[e1 * D + D2 + t];
        float rr  = R[r  * D + t],      ri  = R[r  * D + D2 + t];
        float wr = e1r * rr - e1i * ri;
        float wi = e1r * ri + e1i * rr;
        // w[b][d]: d = t -> wr ; d = t+100 -> wi. Packed layout [d>>2][b][d&3].
        ws[OFF_W + (t >> 2) * 512        + (b << 2) + (t & 3)] = wr;
        ws[OFF_W + ((t >> 2) + 25) * 512 + (b << 2) + (t & 3)] = wi;
    }
    if (t < NL) {
        ws[OFF_A   + (t >> 2) * 512 + (b << 2) + (t & 3)] = lit[e1 * NL + t] - c[t];
        ws[OFF_WNF + (t >> 2) * 512 + (b << 2) + (t & 3)] = nf[r * NL + t];
        if (b == 0) ws[OFF_NQ + t] = -1.4426950408889634f / var[t];
    }
}

__global__ __launch_bounds__(128) void main_kernel(
    const float* __restrict__ E, const float* __restrict__ lit,
    const float* __restrict__ ws, float* __restrict__ out)
{
    const int b  = threadIdx.x;            // lane = batch (coalesced per-lane loads)
    const int e0 = blockIdx.x * ET;

    const float4* w4   = (const float4*)(ws + OFF_W);    // [50][128]
    const float4* a4   = (const float4*)(ws + OFF_A);    // [29][128]
    const float4* wnf4 = (const float4*)(ws + OFF_WNF);  // [29][128]
    const float*  nq   = ws + OFF_NQ;

    // uniform (scalar) entity indices, clamped for the tail block
    int eidx[ET];
#pragma unroll
    for (int j = 0; j < ET; ++j) eidx[j] = min(e0 + j, NE - 1);

    float acc[ET];
#pragma unroll
    for (int j = 0; j < ET; ++j) acc[j] = 0.0f;

    // ---- score_l: acc[j] += sum_d w[b][d] * E[e_j][d] ----
    for (int dc = 0; dc < D; dc += 4) {
        float4 wv = w4[(dc >> 2) * B + b];               // per-lane, coalesced
#pragma unroll
        for (int j = 0; j < ET; ++j) {
            float4 ev = *(const float4*)(E + eidx[j] * D + dc);   // wave-uniform -> s_load
            acc[j] = fmaf(wv.x, ev.x, acc[j]);
            acc[j] = fmaf(wv.y, ev.y, acc[j]);
            acc[j] = fmaf(wv.z, ev.z, acc[j]);
            acc[j] = fmaf(wv.w, ev.w, acc[j]);
        }
    }

    // ---- score_n: acc[j] += sum_l wnf[b][l] * exp2( (a[b][l]-lit[e_j][l])^2 * negq[l] ) ----
    for (int lc = 0; lc < NL; lc += 4) {
        float4 av = a4[(lc >> 2) * B + b];
        float4 wv = wnf4[(lc >> 2) * B + b];
        float4 q  = *(const float4*)(nq + lc);           // wave-uniform
#pragma unroll
        for (int j = 0; j < ET; ++j) {
            float4 lv = *(const float4*)(lit + eidx[j] * NL + lc); // wave-uniform -> s_load
            float t0 = av.x - lv.x;
            float t1 = av.y - lv.y;
            float t2 = av.z - lv.z;
            float t3 = av.w - lv.w;
            acc[j] += wv.x * __builtin_amdgcn_exp2f(t0 * t0 * q.x);
            acc[j] += wv.y * __builtin_amdgcn_exp2f(t1 * t1 * q.y);
            acc[j] += wv.z * __builtin_amdgcn_exp2f(t2 * t2 * q.z);
            acc[j] += wv.w * __builtin_amdgcn_exp2f(t3 * t3 * q.w);
        }
    }

    // ---- sigmoid + store ----
#pragma unroll
    for (int j = 0; j < ET; ++j) {
        float s = 1.0f / (1.0f + __builtin_amdgcn_exp2f(acc[j] * -1.442695040888963f));
        int e = e0 + j;
        if (e < NE) out[b * NE + e] = s;
    }
}

extern "C" void kernel_launch(void* const* d_in, const int* in_sizes, int n_in,
                              void* d_out, int out_size, void* d_ws, size_t ws_size,
                              hipStream_t stream) {
    const int*   e1_idx = (const int*)d_in[0];
    const int*   r_idx  = (const int*)d_in[1];
    const float* E      = (const float*)d_in[2];
    const float* R      = (const float*)d_in[3];
    const float* nf     = (const float*)d_in[4];
    const float* lit    = (const float*)d_in[5];
    const float* c      = (const float*)d_in[6];
    const float* var    = (const float*)d_in[7];
    float* out = (float*)d_out;
    float* ws  = (float*)d_ws;

    prep_kernel<<<B, 128, 0, stream>>>(e1_idx, r_idx, E, R, nf, lit, c, var, ws);

    const int nblocks = (NE + ET - 1) / ET;   // 1869
    main_kernel<<<nblocks, B, 0, stream>>>(E, lit, ws, out);
}

// Round 2
// 70.104 us; speedup vs baseline: 1.2534x; 1.2534x over previous
//
#include <hip/hip_runtime.h>

#define B   128
#define NE  14951
#define NR  1345
#define D   200
#define NL  116
#define D2  100
#define ET  4

// workspace float offsets
#define OFF_W   0        // [50][128][4]  = 25600 floats  (w[b][d], d-major chunks of 4)
#define OFF_A   25600    // [29][128][4]  = 14848 floats  (nh[b][l] - c[l])
#define OFF_WNF 40448    // [29][128][4]  = 14848 floats  (nf_weights[r_idx[b]][l])
#define OFF_NQ  55296    // [116]                        (-log2(e)/var[l])

__global__ __launch_bounds__(128) void prep_kernel(
    const int* __restrict__ e1_idx, const int* __restrict__ r_idx,
    const float* __restrict__ E, const float* __restrict__ R,
    const float* __restrict__ nf, const float* __restrict__ lit,
    const float* __restrict__ c, const float* __restrict__ var,
    float* __restrict__ ws)
{
    const int b = blockIdx.x;
    const int t = threadIdx.x;
    const int e1 = e1_idx[b];
    const int r  = r_idx[b];

    if (t < D2) {
        float e1r = E[e1 * D + t],      e1i = E[e1 * D + D2 + t];
        float rr  = R[r  * D + t],      ri  = R[r  * D + D2 + t];
        float wr = e1r * rr - e1i * ri;
        float wi = e1r * ri + e1i * rr;
        // w[b][d]: d = t -> wr ; d = t+100 -> wi. Packed layout [d>>2][b][d&3].
        ws[OFF_W + (t >> 2) * 512        + (b << 2) + (t & 3)] = wr;
        ws[OFF_W + ((t >> 2) + 25) * 512 + (b << 2) + (t & 3)] = wi;
    }
    if (t < NL) {
        ws[OFF_A   + (t >> 2) * 512 + (b << 2) + (t & 3)] = lit[e1 * NL + t] - c[t];
        ws[OFF_WNF + (t >> 2) * 512 + (b << 2) + (t & 3)] = nf[r * NL + t];
        if (b == 0) ws[OFF_NQ + t] = -1.4426950408889634f / var[t];
    }
}

__global__ __launch_bounds__(128) void main_kernel(
    const float* __restrict__ E, const float* __restrict__ lit,
    const float* __restrict__ ws, float* __restrict__ out)
{
    const int b  = threadIdx.x;            // lane = batch (coalesced per-lane loads)
    const int e0 = blockIdx.x * ET;

    const float4* w4   = (const float4*)(ws + OFF_W);    // [50][128]
    const float4* a4   = (const float4*)(ws + OFF_A);    // [29][128]
    const float4* wnf4 = (const float4*)(ws + OFF_WNF);  // [29][128]
    const float*  nq   = ws + OFF_NQ;

    // uniform (scalar) entity indices, clamped for the tail block
    int eidx[ET];
#pragma unroll
    for (int j = 0; j < ET; ++j) eidx[j] = min(e0 + j, NE - 1);

    float acc[ET];
#pragma unroll
    for (int j = 0; j < ET; ++j) acc[j] = 0.0f;

    // ---- score_l: acc[j] += sum_d w[b][d] * E[e_j][d] ----
    for (int dc = 0; dc < D; dc += 4) {
        float4 wv = w4[(dc >> 2) * B + b];               // per-lane, coalesced
#pragma unroll
        for (int j = 0; j < ET; ++j) {
            float4 ev = *(const float4*)(E + eidx[j] * D + dc);   // wave-uniform -> s_load
            acc[j] = fmaf(wv.x, ev.x, acc[j]);
            acc[j] = fmaf(wv.y, ev.y, acc[j]);
            acc[j] = fmaf(wv.z, ev.z, acc[j]);
            acc[j] = fmaf(wv.w, ev.w, acc[j]);
        }
    }

    // ---- score_n: acc[j] += sum_l wnf[b][l] * exp2( (a[b][l]-lit[e_j][l])^2 * negq[l] ) ----
    for (int lc = 0; lc < NL; lc += 4) {
        float4 av = a4[(lc >> 2) * B + b];
        float4 wv = wnf4[(lc >> 2) * B + b];
        float4 q  = *(const float4*)(nq + lc);           // wave-uniform
#pragma unroll
        for (int j = 0; j < ET; ++j) {
            float4 lv = *(const float4*)(lit + eidx[j] * NL + lc); // wave-uniform -> s_load
            float t0 = av.x - lv.x;
            float t1 = av.y - lv.y;
            float t2 = av.z - lv.z;
            float t3 = av.w - lv.w;
            acc[j] += wv.x * __builtin_amdgcn_exp2f(t0 * t0 * q.x);
            acc[j] += wv.y * __builtin_amdgcn_exp2f(t1 * t1 * q.y);
            acc[j] += wv.z * __builtin_amdgcn_exp2f(t2 * t2 * q.z);
            acc[j] += wv.w * __builtin_amdgcn_exp2f(t3 * t3 * q.w);
        }
    }

    // ---- sigmoid + store ----
#pragma unroll
    for (int j = 0; j < ET; ++j) {
        float s = 1.0f / (1.0f + __builtin_amdgcn_exp2f(acc[j] * -1.442695040888963f));
        int e = e0 + j;
        if (e < NE) out[b * NE + e] = s;
    }
}

extern "C" void kernel_launch(void* const* d_in, const int* in_sizes, int n_in,
                              void* d_out, int out_size, void* d_ws, size_t ws_size,
                              hipStream_t stream) {
    const int*   e1_idx = (const int*)d_in[0];
    const int*   r_idx  = (const int*)d_in[1];
    const float* E      = (const float*)d_in[2];
    const float* R      = (const float*)d_in[3];
    const float* nf     = (const float*)d_in[4];
    const float* lit    = (const float*)d_in[5];
    const float* c      = (const float*)d_in[6];
    const float* var    = (const float*)d_in[7];
    float* out = (float*)d_out;
    float* ws  = (float*)d_ws;

    prep_kernel<<<B, 128, 0, stream>>>(e1_idx, r_idx, E, R, nf, lit, c, var, ws);

    const int nblocks = (NE + ET - 1) / ET;   // 3738
    main_kernel<<<nblocks, B, 0, stream>>>(E, lit, ws, out);
}